// Round 12
// baseline (2392.857 us; speedup 1.0000x reference)
//
#include <hip/hip_runtime.h>
#include <hip/hip_bf16.h>
#include <hip/hip_fp16.h>
#include <math.h>

// Sinkhorn distance, B=4, P1=P2=2048, D=64, EPS=0.1, 100 iterations.
// d_out layout: cost[4] | pi[4*2048*2048] | C[4*2048*2048]
//
// v9 (resubmitted; two acquisition timeouts, still unmeasured): fix v8's
// prologue spill; widen sweep to 8 rows/block.
//  - v8's templated dual-write cost kernel hit VGPR=256 + 320MB scratch
//    spill traffic (255us x2). Revert to v7's proven f32-only cost_kernel
//    (~40us) + dedicated streaming f32->fp16 convert kernels (~17us each).
//  - CT f32 is staged in the dead pi output slot (as in v7), then converted.
//  - lse8_16: 8 rows/block (1024 blocks): 8 independent 16B fp16 loads per
//    thread for 2x the memory-level parallelism of v8's 4-row version.
//    Live VGPR ~90 < 128 cap at __launch_bounds__(256,4).
//  - Loop math unchanged from passing v7/v8: log2 domain, exact-max row LSE,
//    u/eps term cancels; fp16 storage, f32 arithmetic.

#define P 2048
#define D 64
#define B 4
#define ITERS 100
#define EPS 0.1f
// (1/eps) * log2(e) = 1/(eps*ln2): scales C into the log2 domain
#define KS 14.426950408889634f

#define EX2 __builtin_amdgcn_exp2f   // v_exp_f32 (2^x)
#define LG2 __builtin_amdgcn_logf    // v_log_f32 (log2 x)

// ---------------------------------------------------------------- cost matrix
// grid (32, 32, 4), block 256. 64x64 tile, 4x4 per thread. f32 out only
// (v7-proven; no fp16 dual-write -> no spill).
__global__ __launch_bounds__(256) void cost_kernel(
    const float* __restrict__ X, const float* __restrict__ Y,
    float* __restrict__ C) {
  __shared__ float xs[64][65];
  __shared__ float ys[64][65];
  const int b = blockIdx.z;
  const int i0 = blockIdx.y * 64;
  const int j0 = blockIdx.x * 64;
  const float* Xb = X + ((size_t)b * P + i0) * D;
  const float* Yb = Y + ((size_t)b * P + j0) * D;
  const int t = threadIdx.x;
#pragma unroll
  for (int n = 0; n < 4; n++) {
    int e4 = t + n * 256;
    float4 xv = ((const float4*)Xb)[e4];
    float4 yv = ((const float4*)Yb)[e4];
    int r = e4 >> 4;
    int k = (e4 & 15) * 4;
    xs[r][k] = xv.x; xs[r][k + 1] = xv.y; xs[r][k + 2] = xv.z; xs[r][k + 3] = xv.w;
    ys[r][k] = yv.x; ys[r][k + 1] = yv.y; ys[r][k + 2] = yv.z; ys[r][k + 3] = yv.w;
  }
  __syncthreads();
  const int tx = t & 15;
  const int ty = t >> 4;
  float acc[4][4] = {};
#pragma unroll
  for (int k = 0; k < D; k++) {
    float a[4], bb[4];
#pragma unroll
    for (int r = 0; r < 4; r++) a[r] = xs[ty * 4 + r][k];
#pragma unroll
    for (int c = 0; c < 4; c++) bb[c] = ys[tx * 4 + c][k];
#pragma unroll
    for (int r = 0; r < 4; r++)
#pragma unroll
      for (int c = 0; c < 4; c++) {
        float d = a[r] - bb[c];
        acc[r][c] = fmaf(d, d, acc[r][c]);
      }
  }
#pragma unroll
  for (int r = 0; r < 4; r++) {
    float4 o = make_float4(acc[r][0], acc[r][1], acc[r][2], acc[r][3]);
    *(float4*)&C[((size_t)b * P + i0 + ty * 4 + r) * P + j0 + tx * 4] = o;
  }
}

// --------------------------------------------------------- f32 -> fp16 stream
// grid-stride over groups of 8 floats. 2048 blocks x 256 threads.
__global__ __launch_bounds__(256) void conv16(
    const float* __restrict__ src, __half* __restrict__ dst, int n8) {
  int i = blockIdx.x * 256 + threadIdx.x;
  const int stride = gridDim.x * 256;
  for (; i < n8; i += stride) {
    const float4* s = (const float4*)(src + (size_t)i * 8);
    float4 a = s[0], q = s[1];
    ushort4 h0, h1;
    h0.x = __half_as_ushort(__float2half(a.x));
    h0.y = __half_as_ushort(__float2half(a.y));
    h0.z = __half_as_ushort(__float2half(a.z));
    h0.w = __half_as_ushort(__float2half(a.w));
    h1.x = __half_as_ushort(__float2half(q.x));
    h1.y = __half_as_ushort(__float2half(q.y));
    h1.z = __half_as_ushort(__float2half(q.z));
    h1.w = __half_as_ushort(__float2half(q.w));
    ushort4* d = (ushort4*)(dst + (size_t)i * 8);
    d[0] = h0;
    d[1] = h1;
  }
}

// ------------------------------------------------------------------- row LSE
// 1024 blocks x 256 threads. Block owns 8 rows of mat16; thread t owns cols
// [8t, 8t+8). vout[row] = elogK - LSE2_c(vin[c] - KS*mat[row][c]).
__global__ __launch_bounds__(256, 4) void lse8_16(
    const __half* __restrict__ mat16, const float* __restrict__ vin,
    float* __restrict__ vout, float elogK) {
  const int bid = blockIdx.x;
  const int rows0 = bid * 8;          // global row base (b*2048 + row)
  const int b = rows0 >> 11;          // batch (256 blocks per batch)
  const int t = threadIdx.x;
  const int lane = t & 63;
  const int w = t >> 6;

  __shared__ float redm[4][8];
  __shared__ float reds[4][8];

  // vin for my 8 cols (zero at iter 0 via memset)
  float vv[8];
  {
    const float4* vp = (const float4*)(vin + ((size_t)b << 11) + t * 8);
    float4 a = vp[0], q = vp[1];
    vv[0] = a.x; vv[1] = a.y; vv[2] = a.z; vv[3] = a.w;
    vv[4] = q.x; vv[5] = q.y; vv[6] = q.z; vv[7] = q.w;
  }

  // za[r][j] = vv[j] - KS*mat[row][col]; running per-row max in bm
  float za[8][8];
  float bm[8];
  {
    const __half* Mb = mat16 + (size_t)rows0 * P + t * 8;
#pragma unroll
    for (int r = 0; r < 8; r++) {
      float4 raw = *(const float4*)(Mb + (size_t)r * P);  // 8 halves
      const __half* h = (const __half*)&raw;
      float m = -__builtin_inff();
#pragma unroll
      for (int j = 0; j < 8; j++) {
        za[r][j] = fmaf(-KS, __half2float(h[j]), vv[j]);
        m = fmaxf(m, za[r][j]);
      }
      bm[r] = m;
    }
  }

  // exact row max across the wave, then across 4 waves
#pragma unroll
  for (int r = 0; r < 8; r++) {
    float m = bm[r];
#pragma unroll
    for (int off = 32; off; off >>= 1) m = fmaxf(m, __shfl_xor(m, off));
    bm[r] = m;
  }
  if (lane == 0) {
#pragma unroll
    for (int r = 0; r < 8; r++) redm[w][r] = bm[r];
  }
  __syncthreads();
#pragma unroll
  for (int r = 0; r < 8; r++)
    bm[r] = fmaxf(fmaxf(redm[0][r], redm[1][r]),
                  fmaxf(redm[2][r], redm[3][r]));

  // row sums of exp2(za - bm)
#pragma unroll
  for (int r = 0; r < 8; r++) {
    float s = 0.f;
#pragma unroll
    for (int j = 0; j < 8; j++) s += EX2(za[r][j] - bm[r]);
#pragma unroll
    for (int off = 32; off; off >>= 1) s += __shfl_xor(s, off);
    if (lane == 0) reds[w][r] = s;
  }
  __syncthreads();
  if (t == 0) {
    float o[8];
#pragma unroll
    for (int r = 0; r < 8; r++) {
      float S = (reds[0][r] + reds[1][r]) + (reds[2][r] + reds[3][r]);
      o[r] = elogK - bm[r] - LG2(S);
    }
    *(float4*)(vout + rows0) = make_float4(o[0], o[1], o[2], o[3]);
    *(float4*)(vout + rows0 + 4) = make_float4(o[4], o[5], o[6], o[7]);
  }
}

// ------------------------------------------------------------------ epilogue
// 2048 blocks x 256. Block owns 4 rows; thread owns cols [8t,8t+8).
// pi = exp2(u + vv - KS*C16) (consistent with iterated C16 fixed point);
// cost = sum(pi * C_f32). Unchanged from passing v8.
__global__ __launch_bounds__(256) void final_pi16(
    const float* __restrict__ C, const __half* __restrict__ C16,
    const float* __restrict__ uK, const float* __restrict__ vK,
    float* __restrict__ pi, float* __restrict__ cost) {
  const int bid = blockIdx.x;
  const int rows0 = bid * 4;
  const int b = rows0 >> 11;
  const int t = threadIdx.x;
  const int lane = t & 63;
  const int w = t >> 6;

  float vv[8];
  {
    const float4* vp = (const float4*)(vK + ((size_t)b << 11) + t * 8);
    float4 a = vp[0], q = vp[1];
    vv[0] = a.x; vv[1] = a.y; vv[2] = a.z; vv[3] = a.w;
    vv[4] = q.x; vv[5] = q.y; vv[6] = q.z; vv[7] = q.w;
  }

  float acc = 0.f;
#pragma unroll
  for (int r = 0; r < 4; r++) {
    const int row = rows0 + r;
    const float u = uK[row];
    const float* cp = C + (size_t)row * P + t * 8;
    float4 a = *(const float4*)(cp);
    float4 q = *(const float4*)(cp + 4);
    float c32[8] = {a.x, a.y, a.z, a.w, q.x, q.y, q.z, q.w};
    float4 raw = *(const float4*)(C16 + (size_t)row * P + t * 8);
    const __half* h = (const __half*)&raw;
    float p[8];
#pragma unroll
    for (int j = 0; j < 8; j++) {
      p[j] = EX2(fmaf(-KS, __half2float(h[j]), u + vv[j]));
      acc = fmaf(p[j], c32[j], acc);
    }
    float* pp = pi + (size_t)row * P + t * 8;
    *(float4*)(pp) = make_float4(p[0], p[1], p[2], p[3]);
    *(float4*)(pp + 4) = make_float4(p[4], p[5], p[6], p[7]);
  }
#pragma unroll
  for (int off = 32; off; off >>= 1) acc += __shfl_xor(acc, off);
  __shared__ float sa[4];
  if (lane == 0) sa[w] = acc;
  __syncthreads();
  if (t == 0) atomicAdd(cost + b, (sa[0] + sa[1]) + (sa[2] + sa[3]));
}

// -------------------------------------------------------------------- launch
extern "C" void kernel_launch(void* const* d_in, const int* in_sizes, int n_in,
                              void* d_out, int out_size, void* d_ws,
                              size_t ws_size, hipStream_t stream) {
  const float* x = (const float*)d_in[0];
  const float* y = (const float*)d_in[1];
  float* out = (float*)d_out;
  float* cost = out;                          // [4]
  float* pi = out + 4;                        // [B*P*P]; stages CT f32
  float* Cmat = out + 4 + (size_t)B * P * P;  // [B*P*P] f32 C (output)

  __half* C16 = (__half*)d_ws;                // [B*P*P] fp16 C   (33.5 MB)
  __half* CT16 = C16 + (size_t)B * P * P;     // [B*P*P] fp16 C^T (33.5 MB)
  float* vK = (float*)(CT16 + (size_t)B * P * P);  // [8192] log2-scaled v
  float* uK = vK + B * P;                     // [8192] log2-scaled u

  hipMemsetAsync(vK, 0, B * P * sizeof(float), stream);
  hipMemsetAsync(cost, 0, 4 * sizeof(float), stream);

  const int n8 = (B * P * P) / 8;
  dim3 cgrid(P / 64, P / 64, B);
  cost_kernel<<<cgrid, 256, 0, stream>>>(x, y, Cmat);       // C f32
  conv16<<<2048, 256, 0, stream>>>(Cmat, C16, n8);          // C16
  cost_kernel<<<cgrid, 256, 0, stream>>>(y, x, pi);         // CT f32 (pi slot)
  conv16<<<2048, 256, 0, stream>>>(pi, CT16, n8);           // CT16

  // elogK = log(1/P + 1e-8) / (eps*ln2) = log2(1/P + 1e-8)
  const float elogK = log2f(1.0f / (float)P + 1e-8f);

  for (int it = 0; it < ITERS; it++) {
    lse8_16<<<B * P / 8, 256, 0, stream>>>(C16, vK, uK, elogK);   // u
    lse8_16<<<B * P / 8, 256, 0, stream>>>(CT16, uK, vK, elogK);  // v
  }

  final_pi16<<<B * P / 4, 256, 0, stream>>>(Cmat, C16, uK, vK, pi, cost);
}